// Round 5
// baseline (263.593 us; speedup 1.0000x reference)
//
#include <hip/hip_runtime.h>

// out[n,m,:] = normalize(emb[m, g, :]),  g = gene_seq[n,m]
// N=256, M=2000, D=128. Output 262 MB fp32; write floor ~41 us at the
// ~6.4 TB/s the harness fill kernels sustain.
//
// R8: pure A/B vs R7 -- ONLY the store intrinsic changes (regular ->
// nontemporal). Rationale: four structures all landed 93-105 us over the
// big poison fill. Either (A) the timed region is [1GB fill + kernel] and
// our kernel runs at 2.8 TB/s -- plausibly because regular stores
// write-ALLOCATE 262 MB of dirty lines through the 256 MB L3 (eviction
// round-trip the fill avoids with no-allocate policy) -- or (B) the region
// also hides a 262 MB out-poison fill and the kernel is already ~15% over
// its floor. NT stores discriminate: big win => A (allocation pollution),
// neutral => B (roofline; declare next round).
// Structure unchanged from R7: 4 waves x 2 genes/block, rows normalized in
// registers, 128-n chunk, shfl-broadcast gene code, cndmask select.

#define N_SEQ   256
#define M_GENES 2000
#define D_DIM   128
#define GENES_PER_BLOCK 8                    // 4 waves x 2 genes
#define N_CHUNK 128                          // n's per block
#define GRID_X  (M_GENES / GENES_PER_BLOCK)  // 250
#define GRID_Y  (N_SEQ / N_CHUNK)            // 2 -> 500 blocks

typedef float vfloat4 __attribute__((ext_vector_type(4)));

__global__ __launch_bounds__(256) void fused_gather_kernel(
    const int*   __restrict__ gene_seq,    // (N,M)
    const float* __restrict__ emb,         // (M,4,D)
    float*       __restrict__ out)         // (N,M,D)
{
    const int tid  = threadIdx.x;
    const int wave = tid >> 6;             // 0..3
    const int lane = tid & 63;
    const int c    = lane & 31;            // float4 index within a 512 B row

    const int m0    = blockIdx.x * GENES_PER_BLOCK;
    const int n0    = blockIdx.y * N_CHUNK;
    const int m_sel = m0 + (wave << 1) + (lane >> 5);   // my half's gene

    // ---- Preload + normalize the 4 candidate rows of my gene (registers) ----
    vfloat4 r0, r1, r2, r3;
    {
        const float* rowp = emb + ((size_t)(m_sel << 2) << 7) + (c << 2);
        #pragma unroll
        for (int g = 0; g < 4; ++g) {
            const vfloat4 v = *reinterpret_cast<const vfloat4*>(rowp + (g << 7));
            float ss = v.x * v.x + v.y * v.y + v.z * v.z + v.w * v.w;
            ss += __shfl_xor(ss, 1, 32);   // width 32: halves reduce independently
            ss += __shfl_xor(ss, 2, 32);
            ss += __shfl_xor(ss, 4, 32);
            ss += __shfl_xor(ss, 8, 32);
            ss += __shfl_xor(ss, 16, 32);
            const float inv = 1.0f / fmaxf(sqrtf(ss), 1e-12f);
            const vfloat4 o = v * inv;
            if (g == 0) r0 = o; else if (g == 1) r1 = o;
            else if (g == 2) r2 = o; else r3 = o;
        }
    }

    // ---- Preload g for all 128 n's of this chunk (4 regs/lane) ----
    // lane (half,c) holds g(n0 + 32k + c, m_sel), k = 0..3
    const int ga = gene_seq[(n0 +      c) * M_GENES + m_sel];
    const int gb = gene_seq[(n0 + 32 + c) * M_GENES + m_sel];
    const int gc = gene_seq[(n0 + 64 + c) * M_GENES + m_sel];
    const int gd = gene_seq[(n0 + 96 + c) * M_GENES + m_sel];

    float* __restrict__ outbase =
        out + (size_t)n0 * (M_GENES * D_DIM) + (size_t)(m_sel << 7) + (c << 2);

    // ---- Stream the n-loop: broadcast g, cndmask-select row, NT store ----
    #pragma unroll
    for (int k = 0; k < 4; ++k) {
        const int gsrc = (k == 0) ? ga : (k == 1) ? gb : (k == 2) ? gc : gd;
        #pragma unroll 8
        for (int i = 0; i < 32; ++i) {
            const int gv = __shfl(gsrc, (lane & 32) | i, 64);   // same half, lane i

            const vfloat4 lo = (gv & 1) ? r1 : r0;
            const vfloat4 hi = (gv & 1) ? r3 : r2;
            const vfloat4 v  = (gv & 2) ? hi : lo;

            __builtin_nontemporal_store(v, reinterpret_cast<vfloat4*>(
                outbase + (size_t)((k << 5) + i) * (M_GENES * D_DIM)));
        }
    }
}

extern "C" void kernel_launch(void* const* d_in, const int* in_sizes, int n_in,
                              void* d_out, int out_size, void* d_ws, size_t ws_size,
                              hipStream_t stream) {
    const int*   gene_seq = (const int*)d_in[0];
    const float* emb      = (const float*)d_in[1];
    float*       out      = (float*)d_out;

    fused_gather_kernel<<<dim3(GRID_X, GRID_Y), dim3(256), 0, stream>>>(
        gene_seq, emb, out);
}